// Round 2
// baseline (23339.351 us; speedup 1.0000x reference)
//
#include <hip/hip_runtime.h>
#include <hip/hip_bf16.h>
#include <cstdint>

#define BATCH 64
#define SEQ   512
#define DIM   512
#define MTOT  (BATCH*SEQ)   // 32768

// W residency split (in j4-blocks of 4 j-rows each; 128 total):
#define RB 48   // register-resident j4-blocks (j 0..191)   -> 192 VGPRs/thread
#define LB 7    // LDS-resident j4-blocks (j 192..219)      -> 56 KB
#define SB (128 - RB - LB)  // streamed from L2 each step (j 220..511) = 73

// ---------------------------------------------------------------------------
// Kernel 0: pack W_hh [c][j] -> Wpk[jb][c] (float4 over j%4)
//   Wpk[jb*512 + c] = { W[c][4jb], W[c][4jb+1], W[c][4jb+2], W[c][4jb+3] }
// grid: 512 blocks (c), 128 threads (jb). Reads coalesced float4.
// ---------------------------------------------------------------------------
__global__ __launch_bounds__(128) void pack_w(const float* __restrict__ W,
                                              float4* __restrict__ Wpk) {
    const int c  = blockIdx.x;
    const int jb = threadIdx.x;
    const float4 v = *(const float4*)&W[(size_t)c * DIM + 4 * jb];
    Wpk[(size_t)jb * DIM + c] = v;
}

// ---------------------------------------------------------------------------
// Kernel 1: fused embedding gather + input projection (NT GEMM, fp32)
//   xp[m][n] = sum_k emb[x[m]][k] * W_ih[n][k]  + b_ih[n] + b_hh[n]
// ---------------------------------------------------------------------------
__global__ __launch_bounds__(256) void embed_proj(
    const int*   __restrict__ xidx,
    const float* __restrict__ emb,
    const float* __restrict__ W_ih,
    const float* __restrict__ b_ih,
    const float* __restrict__ b_hh,
    float*       __restrict__ xp) {
    __shared__ float As[64][68];  // As[k][m]
    __shared__ float Bs[64][68];  // Bs[k][n]

    const int m0  = blockIdx.x * 64;
    const int n0  = blockIdx.y * 64;
    const int tid = threadIdx.x;

    const int lr = tid >> 4;
    const int lc = (tid & 15) << 2;

    int rows[4];
#pragma unroll
    for (int i = 0; i < 4; i++) rows[i] = xidx[m0 + lr + 16 * i];

    const int tm = (tid & 15) << 2;
    const int tn = (tid >> 4) << 2;

    float acc[4][4];
#pragma unroll
    for (int i = 0; i < 4; i++)
#pragma unroll
        for (int j = 0; j < 4; j++) acc[i][j] = 0.0f;

    for (int k0 = 0; k0 < DIM; k0 += 64) {
#pragma unroll
        for (int i = 0; i < 4; i++) {
            const int rl = lr + 16 * i;
            const float4 a = *(const float4*)&emb[(size_t)rows[i] * DIM + k0 + lc];
            As[lc + 0][rl] = a.x; As[lc + 1][rl] = a.y;
            As[lc + 2][rl] = a.z; As[lc + 3][rl] = a.w;
            const float4 b = *(const float4*)&W_ih[(size_t)(n0 + rl) * DIM + k0 + lc];
            Bs[lc + 0][rl] = b.x; Bs[lc + 1][rl] = b.y;
            Bs[lc + 2][rl] = b.z; Bs[lc + 3][rl] = b.w;
        }
        __syncthreads();
#pragma unroll 8
        for (int kk = 0; kk < 64; kk++) {
            const float4 a = *(const float4*)&As[kk][tm];
            const float4 b = *(const float4*)&Bs[kk][tn];
            acc[0][0] = fmaf(a.x, b.x, acc[0][0]);
            acc[0][1] = fmaf(a.x, b.y, acc[0][1]);
            acc[0][2] = fmaf(a.x, b.z, acc[0][2]);
            acc[0][3] = fmaf(a.x, b.w, acc[0][3]);
            acc[1][0] = fmaf(a.y, b.x, acc[1][0]);
            acc[1][1] = fmaf(a.y, b.y, acc[1][1]);
            acc[1][2] = fmaf(a.y, b.z, acc[1][2]);
            acc[1][3] = fmaf(a.y, b.w, acc[1][3]);
            acc[2][0] = fmaf(a.z, b.x, acc[2][0]);
            acc[2][1] = fmaf(a.z, b.y, acc[2][1]);
            acc[2][2] = fmaf(a.z, b.z, acc[2][2]);
            acc[2][3] = fmaf(a.z, b.w, acc[2][3]);
            acc[3][0] = fmaf(a.w, b.x, acc[3][0]);
            acc[3][1] = fmaf(a.w, b.y, acc[3][1]);
            acc[3][2] = fmaf(a.w, b.z, acc[3][2]);
            acc[3][3] = fmaf(a.w, b.w, acc[3][3]);
        }
        __syncthreads();
    }

    const int n = n0 + tn;
    const float bias0 = b_ih[n + 0] + b_hh[n + 0];
    const float bias1 = b_ih[n + 1] + b_hh[n + 1];
    const float bias2 = b_ih[n + 2] + b_hh[n + 2];
    const float bias3 = b_ih[n + 3] + b_hh[n + 3];
#pragma unroll
    for (int i = 0; i < 4; i++) {
        float4 o;
        o.x = acc[i][0] + bias0;
        o.y = acc[i][1] + bias1;
        o.z = acc[i][2] + bias2;
        o.w = acc[i][3] + bias3;
        *(float4*)&xp[(size_t)(m0 + tm + i) * DIM + n] = o;
    }
}

// ---------------------------------------------------------------------------
// Kernel 2: sequential RNN scan, W mostly resident on-CU.
//  32 wgs x 512 threads; wg = batch rows (2*blk, 2*blk+1); thread = column tid.
//  W split: 192 j-rows in VGPRs, 28 in LDS, 292 streamed (packed dwordx4).
//  h vectors in LDS (broadcast float4 reads). In-place xp->hid in buf.
// ---------------------------------------------------------------------------
__global__ __launch_bounds__(512, 2) void rnn_scan(const float4* __restrict__ Wpk,
                                                   float* __restrict__ buf) {
    __shared__ float4 h0s[DIM / 4];      // h row b0   (2 KB)
    __shared__ float4 h1s[DIM / 4];      // h row b0+1 (2 KB)
    __shared__ float4 wlds[LB * DIM];    // 56 KB, [i][c]

    const int tid = threadIdx.x;
    const int b0  = blockIdx.x * 2;

    // preload register-resident W: j4-blocks 0..RB-1, this thread's column
    float4 wreg[RB];
#pragma unroll
    for (int i = 0; i < RB; i++) wreg[i] = Wpk[(size_t)i * DIM + tid];

    // LDS-resident W: j4-blocks RB..RB+LB-1
#pragma unroll
    for (int i = 0; i < LB; i++) wlds[i * DIM + tid] = Wpk[(size_t)(RB + i) * DIM + tid];

    ((float*)h0s)[tid] = 0.0f;
    ((float*)h1s)[tid] = 0.0f;
    __syncthreads();

    float* row0 = buf + (size_t)b0 * SEQ * DIM;
    float* row1 = buf + (size_t)(b0 + 1) * SEQ * DIM;

    for (int t = 0; t < SEQ; t++) {
        const int off = t * DIM + tid;
        float4 a0 = make_float4(0.f, 0.f, 0.f, 0.f);
        float4 a1 = make_float4(0.f, 0.f, 0.f, 0.f);
        const float x0 = row0[off];
        const float x1 = row1[off];

        // ---- streamed portion: j4-blocks RB+LB .. 127 (dwordx4 from L2) ----
#pragma unroll 8
        for (int i = RB + LB; i < 128; i++) {
            const float4 wv = Wpk[(size_t)i * DIM + tid];
            const float4 ha = h0s[i];
            const float4 hb = h1s[i];
            a0.x = fmaf(wv.x, ha.x, a0.x); a0.y = fmaf(wv.y, ha.y, a0.y);
            a0.z = fmaf(wv.z, ha.z, a0.z); a0.w = fmaf(wv.w, ha.w, a0.w);
            a1.x = fmaf(wv.x, hb.x, a1.x); a1.y = fmaf(wv.y, hb.y, a1.y);
            a1.z = fmaf(wv.z, hb.z, a1.z); a1.w = fmaf(wv.w, hb.w, a1.w);
        }

        // ---- register-resident portion ----
#pragma unroll
        for (int i = 0; i < RB; i++) {
            const float4 wv = wreg[i];
            const float4 ha = h0s[i];
            const float4 hb = h1s[i];
            a0.x = fmaf(wv.x, ha.x, a0.x); a0.y = fmaf(wv.y, ha.y, a0.y);
            a0.z = fmaf(wv.z, ha.z, a0.z); a0.w = fmaf(wv.w, ha.w, a0.w);
            a1.x = fmaf(wv.x, hb.x, a1.x); a1.y = fmaf(wv.y, hb.y, a1.y);
            a1.z = fmaf(wv.z, hb.z, a1.z); a1.w = fmaf(wv.w, hb.w, a1.w);
        }

        // ---- LDS-resident portion ----
#pragma unroll
        for (int i = 0; i < LB; i++) {
            const float4 wv = wlds[i * DIM + tid];
            const float4 ha = h0s[RB + i];
            const float4 hb = h1s[RB + i];
            a0.x = fmaf(wv.x, ha.x, a0.x); a0.y = fmaf(wv.y, ha.y, a0.y);
            a0.z = fmaf(wv.z, ha.z, a0.z); a0.w = fmaf(wv.w, ha.w, a0.w);
            a1.x = fmaf(wv.x, hb.x, a1.x); a1.y = fmaf(wv.y, hb.y, a1.y);
            a1.z = fmaf(wv.z, hb.z, a1.z); a1.w = fmaf(wv.w, hb.w, a1.w);
        }

        const float pre0 = x0 + ((a0.x + a0.y) + (a0.z + a0.w));
        const float pre1 = x1 + ((a1.x + a1.y) + (a1.z + a1.w));
        const float hn0 = tanhf(pre0);
        const float hn1 = tanhf(pre1);

        __syncthreads();            // all h reads done before overwrite
        ((float*)h0s)[tid] = hn0;
        ((float*)h1s)[tid] = hn1;
        row0[off] = hn0;
        row1[off] = hn1;
        __syncthreads();            // h visible before next step
    }
}

// ---------------------------------------------------------------------------
// Kernel 3: softmax over H (per b,t) + transpose [B][T][H] -> out [B][H][T]
// ---------------------------------------------------------------------------
__global__ __launch_bounds__(256) void softmax_T(const float* __restrict__ hid,
                                                 float* __restrict__ out) {
    __shared__ float rowmax[64];
    __shared__ float rowinv[64];
    __shared__ float tile[64][65];

    const int b   = blockIdx.x;
    const int t0  = blockIdx.y * 64;
    const int tid = threadIdx.x;
    const float* base = hid + ((size_t)b * SEQ + t0) * DIM;

    const int r = tid >> 2;
    const int p = tid & 3;

    float m = -1e30f;
#pragma unroll 4
    for (int k = 0; k < 32; k++) {
        const float4 v = *(const float4*)&base[r * DIM + ((k * 4 + p) << 2)];
        m = fmaxf(m, fmaxf(fmaxf(v.x, v.y), fmaxf(v.z, v.w)));
    }
    m = fmaxf(m, __shfl_xor(m, 1));
    m = fmaxf(m, __shfl_xor(m, 2));

    float s = 0.0f;
#pragma unroll 4
    for (int k = 0; k < 32; k++) {
        const float4 v = *(const float4*)&base[r * DIM + ((k * 4 + p) << 2)];
        s += expf(v.x - m) + expf(v.y - m) + expf(v.z - m) + expf(v.w - m);
    }
    s += __shfl_xor(s, 1);
    s += __shfl_xor(s, 2);
    if (p == 0) {
        rowmax[r] = m;
        rowinv[r] = 1.0f / s;
    }
    __syncthreads();

    for (int hc = 0; hc < 8; hc++) {
#pragma unroll
        for (int i = 0; i < 16; i++) {
            const int lin = tid + 256 * i;
            const int rr  = lin >> 6;
            const int cc  = lin & 63;
            const float v = base[rr * DIM + hc * 64 + cc];
            tile[cc][rr] = expf(v - rowmax[rr]) * rowinv[rr];
        }
        __syncthreads();
#pragma unroll
        for (int i = 0; i < 16; i++) {
            const int lin = tid + 256 * i;
            const int hh  = lin >> 6;
            const int tt  = lin & 63;
            out[((size_t)b * DIM + hc * 64 + hh) * SEQ + t0 + tt] = tile[hh][tt];
        }
        __syncthreads();
    }
}

// ---------------------------------------------------------------------------
extern "C" void kernel_launch(void* const* d_in, const int* in_sizes, int n_in,
                              void* d_out, int out_size, void* d_ws, size_t ws_size,
                              hipStream_t stream) {
    const int*   x    = (const int*)  d_in[0];
    const float* emb  = (const float*)d_in[1];
    const float* W_ih = (const float*)d_in[2];
    const float* W_hh = (const float*)d_in[3];
    const float* b_ih = (const float*)d_in[4];
    const float* b_hh = (const float*)d_in[5];
    float* out = (float*)d_out;

    // 64 MB scratch: xp (then hid, in place) as [B][T][H]
    float* buf = (float*)d_ws;
    // packed W_hh staged in d_out (1 M floats << out_size); consumed by
    // rnn_scan before softmax_T overwrites d_out (stream-ordered).
    float4* Wpk = (float4*)out;

    pack_w<<<dim3(DIM), 128, 0, stream>>>(W_hh, Wpk);
    embed_proj<<<dim3(MTOT / 64, DIM / 64), 256, 0, stream>>>(x, emb, W_ih, b_ih, b_hh, buf);
    rnn_scan<<<32, 512, 0, stream>>>(Wpk, buf);
    softmax_T<<<dim3(BATCH, SEQ / 64), 256, 0, stream>>>(buf, out);
}